// Round 1
// baseline (2693.155 us; speedup 1.0000x reference)
//
#include <hip/hip_runtime.h>
#include <math.h>

#define NB   8
#define NPTS 4096
#define MPER 1024
#define MTOT (NB*MPER)
#define CIN  64
#define KNN  64
#define CAP  512
// (0.2*0.2) computed in double, as the reference's python-float R*R
#define R2D  0.04000000000000001

// exact IEEE fp32 distance, reference order: ((dx*dx + dy*dy) + dz*dz), no FMA
__device__ __forceinline__ float d2f(float ax, float ay, float az,
                                     float bx, float by, float bz) {
    float dx = __fsub_rn(ax, bx);
    float dy = __fsub_rn(ay, by);
    float dz = __fsub_rn(az, bz);
    return __fadd_rn(__fadd_rn(__fmul_rn(dx, dx), __fmul_rn(dy, dy)),
                     __fmul_rn(dz, dz));
}

// ---------------- Kernel 1: farthest point sampling ----------------
// one block per cloud; 1024 threads, 4 points each (held in registers)
__global__ __launch_bounds__(1024) void fps_kernel(const float* __restrict__ pos,
                                                   int* __restrict__ sel)
{
    const int b = blockIdx.x;
    const int t = threadIdx.x;
    const float* pb = pos + (size_t)b * NPTS * 3;

    float px[4], py[4], pz[4], mind[4];
#pragma unroll
    for (int r = 0; r < 4; ++r) {
        int j = r * 1024 + t;
        px[r] = pb[j * 3 + 0];
        py[r] = pb[j * 3 + 1];
        pz[r] = pb[j * 3 + 2];
        mind[r] = 3.0e38f;   // first min() gives exactly d2-to-p0
    }

    __shared__ float swv[16];
    __shared__ int   swi[16];
    __shared__ float scur[3];
    __shared__ int   spick;

    if (t == 0) {
        scur[0] = px[0]; scur[1] = py[0]; scur[2] = pz[0];
        sel[b * MPER + 0] = b * NPTS + 0;
    }
    __syncthreads();

    for (int it = 1; it < MPER; ++it) {
        const float cx = scur[0], cy = scur[1], cz = scur[2];
        float bv = -1.0f; int bi = 0x7fffffff;
#pragma unroll
        for (int r = 0; r < 4; ++r) {
            float d2 = d2f(px[r], py[r], pz[r], cx, cy, cz);
            float m = fminf(mind[r], d2);
            mind[r] = m;
            int j = r * 1024 + t;
            if (m > bv || (m == bv && j < bi)) { bv = m; bi = j; }
        }
        // wave argmax (tie -> lower index)
#pragma unroll
        for (int off = 32; off > 0; off >>= 1) {
            float ov = __shfl_xor(bv, off);
            int   oi = __shfl_xor(bi, off);
            if (ov > bv || (ov == bv && oi < bi)) { bv = ov; bi = oi; }
        }
        if ((t & 63) == 0) { swv[t >> 6] = bv; swi[t >> 6] = bi; }
        __syncthreads();
        if (t == 0) {
            float fv = swv[0]; int fi = swi[0];
#pragma unroll
            for (int w = 1; w < 16; ++w) {
                float ov = swv[w]; int oi = swi[w];
                if (ov > fv || (ov == fv && oi < fi)) { fv = ov; fi = oi; }
            }
            spick = fi;
            sel[b * MPER + it] = b * NPTS + fi;
        }
        __syncthreads();
        const int pick = spick;
        if (t == (pick & 1023)) {
            int r = pick >> 10;
            scur[0] = px[r]; scur[1] = py[r]; scur[2] = pz[r];
        }
        __syncthreads();
    }
}

// ---------------- Kernel 2: ball query + K nearest (rank select) ----------------
// one wave per centroid, 4 waves / block
__global__ __launch_bounds__(256) void ballq_kernel(
    const float* __restrict__ pos, const int* __restrict__ sel,
    int* __restrict__ nbr, int* __restrict__ cnt,
    float* __restrict__ out_pos, float* __restrict__ out_batch)
{
    __shared__ float cd[4][CAP];
    __shared__ int   ci[4][CAP];

    const int wv   = threadIdx.x >> 6;
    const int lane = threadIdx.x & 63;
    const int c    = blockIdx.x * 4 + wv;
    const int sg   = sel[c];
    const int b    = c >> 10;            // c / MPER
    const int base = b * NPTS;
    const float* pb = pos + (size_t)base * 3;
    const float qx = pos[(size_t)sg * 3 + 0];
    const float qy = pos[(size_t)sg * 3 + 1];
    const float qz = pos[(size_t)sg * 3 + 2];

    int n = 0;
    for (int r0 = 0; r0 < NPTS; r0 += 64) {
        const int j = r0 + lane;
        float x = pb[j * 3 + 0], y = pb[j * 3 + 1], z = pb[j * 3 + 2];
        float d2 = d2f(x, y, z, qx, qy, qz);
        bool inside = ((double)d2 <= R2D);
        unsigned long long m = __ballot(inside);
        if (inside) {
            int myoff = n + __popcll(m & ((1ull << lane) - 1ull));
            if (myoff < CAP) { cd[wv][myoff] = d2; ci[wv][myoff] = j; }
        }
        n += __popcll(m);
    }
    n = min(n, CAP);
    __syncthreads();   // drain LDS writes; all waves structurally aligned here

    // rank = #{j : (dj,ij) <lex (d,id)}  -> matches lax.top_k stable ordering
    for (int i = lane; i < n; i += 64) {
        float d = cd[wv][i]; int id = ci[wv][i];
        int rank = 0;
        for (int j = 0; j < n; ++j) {
            float dj = cd[wv][j]; int ij = ci[wv][j];
            rank += (dj < d || (dj == d && ij < id)) ? 1 : 0;
        }
        if (rank < KNN) nbr[(size_t)c * KNN + rank] = base + id;
    }
    if (lane == 0) {
        cnt[c] = min(n, KNN);
        out_pos[c * 3 + 0] = qx;
        out_pos[c * 3 + 1] = qy;
        out_pos[c * 3 + 2] = qz;
        out_batch[c] = (float)b;
    }
}

// ---------------- Kernel 3: gather + MLP (67->64->64->128) + masked max ----------------
// one block per centroid, 256 threads; fp32 VALU, LDS-staged activations/weights
#define SH_INF 0            // 64*67 = 4288 floats
#define SH_W   4288         // 2048 floats (weight chunk: 32x64 or 16x128)
#define SH_H1  6336         // 64*65 = 4160 floats (stride 65 to spread banks)
#define SH_H2  10496        // 4160 floats
#define SH_TOT 14656        // 58.6 KB

__global__ __launch_bounds__(256) void mlp_kernel(
    const float* __restrict__ x, const float* __restrict__ pos,
    const int* __restrict__ nbr, const int* __restrict__ cnt,
    const float* __restrict__ out_pos,
    const float* __restrict__ W1, const float* __restrict__ b1,
    const float* __restrict__ W2, const float* __restrict__ b2,
    const float* __restrict__ W3, const float* __restrict__ b3,
    float* __restrict__ out_x)
{
    __shared__ float sm[SH_TOT];

    const int c = blockIdx.x;
    const int n = cnt[c];
    const int t = threadIdx.x;

    // ---- stage input features: inf[k][0..66] = [x[nbr_k], pos[nbr_k]-q] ----
    {
        const int k = t >> 2, g = t & 3;
        int nb = (k < n) ? nbr[(size_t)c * KNN + k] : 0;
        float q0 = out_pos[c * 3 + 0], q1 = out_pos[c * 3 + 1], q2 = out_pos[c * 3 + 2];
#pragma unroll
        for (int i = 0; i < 17; ++i) {
            int j = g + 4 * i;
            if (j < 67) {
                float v = 0.0f;
                if (k < n) {
                    if (j < 64) v = x[(size_t)nb * CIN + j];
                    else {
                        float qd = (j == 64) ? q0 : ((j == 65) ? q1 : q2);
                        v = pos[(size_t)nb * 3 + (j - 64)] - qd;   // exact fp32 sub
                    }
                }
                sm[SH_INF + k * 67 + j] = v;
            }
        }
    }

    const int tc = t & 15, tk = t >> 4;
    const int c0 = tc * 4, k0 = tk * 4;

    // ---- layer 1: 67 -> 64, ReLU ----
    float acc[4][4];
    {
        float4 bb = *(const float4*)(b1 + c0);
#pragma unroll
        for (int i = 0; i < 4; ++i) {
            acc[i][0] = bb.x; acc[i][1] = bb.y; acc[i][2] = bb.z; acc[i][3] = bb.w;
        }
        int kk0 = 0;
        for (int ch = 0; ch < 3; ++ch) {
            int rows = min(32, 67 - kk0);
            __syncthreads();
            for (int e = t; e < rows * 64; e += 256) sm[SH_W + e] = W1[kk0 * 64 + e];
            __syncthreads();
            for (int r = 0; r < rows; ++r) {
                int kk = kk0 + r;
                float4 w = *(const float4*)&sm[SH_W + r * 64 + c0];
                float in0 = sm[SH_INF + (k0 + 0) * 67 + kk];
                float in1 = sm[SH_INF + (k0 + 1) * 67 + kk];
                float in2 = sm[SH_INF + (k0 + 2) * 67 + kk];
                float in3 = sm[SH_INF + (k0 + 3) * 67 + kk];
                acc[0][0] = fmaf(in0, w.x, acc[0][0]); acc[0][1] = fmaf(in0, w.y, acc[0][1]);
                acc[0][2] = fmaf(in0, w.z, acc[0][2]); acc[0][3] = fmaf(in0, w.w, acc[0][3]);
                acc[1][0] = fmaf(in1, w.x, acc[1][0]); acc[1][1] = fmaf(in1, w.y, acc[1][1]);
                acc[1][2] = fmaf(in1, w.z, acc[1][2]); acc[1][3] = fmaf(in1, w.w, acc[1][3]);
                acc[2][0] = fmaf(in2, w.x, acc[2][0]); acc[2][1] = fmaf(in2, w.y, acc[2][1]);
                acc[2][2] = fmaf(in2, w.z, acc[2][2]); acc[2][3] = fmaf(in2, w.w, acc[2][3]);
                acc[3][0] = fmaf(in3, w.x, acc[3][0]); acc[3][1] = fmaf(in3, w.y, acc[3][1]);
                acc[3][2] = fmaf(in3, w.z, acc[3][2]); acc[3][3] = fmaf(in3, w.w, acc[3][3]);
            }
            kk0 += rows;
        }
#pragma unroll
        for (int i = 0; i < 4; ++i)
#pragma unroll
            for (int j = 0; j < 4; ++j)
                sm[SH_H1 + (k0 + i) * 65 + (c0 + j)] = fmaxf(acc[i][j], 0.0f);
    }

    // ---- layer 2: 64 -> 64, ReLU ----
    {
        float4 bb = *(const float4*)(b2 + c0);
#pragma unroll
        for (int i = 0; i < 4; ++i) {
            acc[i][0] = bb.x; acc[i][1] = bb.y; acc[i][2] = bb.z; acc[i][3] = bb.w;
        }
        for (int ch = 0; ch < 2; ++ch) {
            __syncthreads();
            for (int e = t; e < 32 * 64; e += 256) sm[SH_W + e] = W2[ch * 2048 + e];
            __syncthreads();
            for (int r = 0; r < 32; ++r) {
                int kk = ch * 32 + r;
                float4 w = *(const float4*)&sm[SH_W + r * 64 + c0];
                float in0 = sm[SH_H1 + (k0 + 0) * 65 + kk];
                float in1 = sm[SH_H1 + (k0 + 1) * 65 + kk];
                float in2 = sm[SH_H1 + (k0 + 2) * 65 + kk];
                float in3 = sm[SH_H1 + (k0 + 3) * 65 + kk];
                acc[0][0] = fmaf(in0, w.x, acc[0][0]); acc[0][1] = fmaf(in0, w.y, acc[0][1]);
                acc[0][2] = fmaf(in0, w.z, acc[0][2]); acc[0][3] = fmaf(in0, w.w, acc[0][3]);
                acc[1][0] = fmaf(in1, w.x, acc[1][0]); acc[1][1] = fmaf(in1, w.y, acc[1][1]);
                acc[1][2] = fmaf(in1, w.z, acc[1][2]); acc[1][3] = fmaf(in1, w.w, acc[1][3]);
                acc[2][0] = fmaf(in2, w.x, acc[2][0]); acc[2][1] = fmaf(in2, w.y, acc[2][1]);
                acc[2][2] = fmaf(in2, w.z, acc[2][2]); acc[2][3] = fmaf(in2, w.w, acc[2][3]);
                acc[3][0] = fmaf(in3, w.x, acc[3][0]); acc[3][1] = fmaf(in3, w.y, acc[3][1]);
                acc[3][2] = fmaf(in3, w.z, acc[3][2]); acc[3][3] = fmaf(in3, w.w, acc[3][3]);
            }
        }
        __syncthreads();
#pragma unroll
        for (int i = 0; i < 4; ++i)
#pragma unroll
            for (int j = 0; j < 4; ++j)
                sm[SH_H2 + (k0 + i) * 65 + (c0 + j)] = fmaxf(acc[i][j], 0.0f);
    }

    // ---- layer 3: 64 -> 128 (two c-tiles per thread) ----
    float acc3[2][4][4];
    {
#pragma unroll
        for (int u = 0; u < 2; ++u) {
            float4 bb = *(const float4*)(b3 + c0 + u * 64);
#pragma unroll
            for (int i = 0; i < 4; ++i) {
                acc3[u][i][0] = bb.x; acc3[u][i][1] = bb.y;
                acc3[u][i][2] = bb.z; acc3[u][i][3] = bb.w;
            }
        }
        for (int ch = 0; ch < 4; ++ch) {
            __syncthreads();
            for (int e = t; e < 16 * 128; e += 256) sm[SH_W + e] = W3[ch * 2048 + e];
            __syncthreads();
            for (int r = 0; r < 16; ++r) {
                int kk = ch * 16 + r;
                float4 wa = *(const float4*)&sm[SH_W + r * 128 + c0];
                float4 wb = *(const float4*)&sm[SH_W + r * 128 + c0 + 64];
                float in0 = sm[SH_H2 + (k0 + 0) * 65 + kk];
                float in1 = sm[SH_H2 + (k0 + 1) * 65 + kk];
                float in2 = sm[SH_H2 + (k0 + 2) * 65 + kk];
                float in3 = sm[SH_H2 + (k0 + 3) * 65 + kk];
                acc3[0][0][0] = fmaf(in0, wa.x, acc3[0][0][0]); acc3[0][0][1] = fmaf(in0, wa.y, acc3[0][0][1]);
                acc3[0][0][2] = fmaf(in0, wa.z, acc3[0][0][2]); acc3[0][0][3] = fmaf(in0, wa.w, acc3[0][0][3]);
                acc3[0][1][0] = fmaf(in1, wa.x, acc3[0][1][0]); acc3[0][1][1] = fmaf(in1, wa.y, acc3[0][1][1]);
                acc3[0][1][2] = fmaf(in1, wa.z, acc3[0][1][2]); acc3[0][1][3] = fmaf(in1, wa.w, acc3[0][1][3]);
                acc3[0][2][0] = fmaf(in2, wa.x, acc3[0][2][0]); acc3[0][2][1] = fmaf(in2, wa.y, acc3[0][2][1]);
                acc3[0][2][2] = fmaf(in2, wa.z, acc3[0][2][2]); acc3[0][2][3] = fmaf(in2, wa.w, acc3[0][2][3]);
                acc3[0][3][0] = fmaf(in3, wa.x, acc3[0][3][0]); acc3[0][3][1] = fmaf(in3, wa.y, acc3[0][3][1]);
                acc3[0][3][2] = fmaf(in3, wa.z, acc3[0][3][2]); acc3[0][3][3] = fmaf(in3, wa.w, acc3[0][3][3]);
                acc3[1][0][0] = fmaf(in0, wb.x, acc3[1][0][0]); acc3[1][0][1] = fmaf(in0, wb.y, acc3[1][0][1]);
                acc3[1][0][2] = fmaf(in0, wb.z, acc3[1][0][2]); acc3[1][0][3] = fmaf(in0, wb.w, acc3[1][0][3]);
                acc3[1][1][0] = fmaf(in1, wb.x, acc3[1][1][0]); acc3[1][1][1] = fmaf(in1, wb.y, acc3[1][1][1]);
                acc3[1][1][2] = fmaf(in1, wb.z, acc3[1][1][2]); acc3[1][1][3] = fmaf(in1, wb.w, acc3[1][1][3]);
                acc3[1][2][0] = fmaf(in2, wb.x, acc3[1][2][0]); acc3[1][2][1] = fmaf(in2, wb.y, acc3[1][2][1]);
                acc3[1][2][2] = fmaf(in2, wb.z, acc3[1][2][2]); acc3[1][2][3] = fmaf(in2, wb.w, acc3[1][2][3]);
                acc3[1][3][0] = fmaf(in3, wb.x, acc3[1][3][0]); acc3[1][3][1] = fmaf(in3, wb.y, acc3[1][3][1]);
                acc3[1][3][2] = fmaf(in3, wb.z, acc3[1][3][2]); acc3[1][3][3] = fmaf(in3, wb.w, acc3[1][3][3]);
            }
        }
    }

    // ---- masked max over k (k < n), tree-reduced via LDS partials ----
    float pm[2][4];
#pragma unroll
    for (int u = 0; u < 2; ++u)
#pragma unroll
        for (int j = 0; j < 4; ++j) pm[u][j] = -1e30f;
#pragma unroll
    for (int i = 0; i < 4; ++i) {
        if (k0 + i < n) {
#pragma unroll
            for (int u = 0; u < 2; ++u)
#pragma unroll
                for (int j = 0; j < 4; ++j) pm[u][j] = fmaxf(pm[u][j], acc3[u][i][j]);
        }
    }
    __syncthreads();   // h1 region is dead; reuse as [16][128] partials
#pragma unroll
    for (int u = 0; u < 2; ++u)
#pragma unroll
        for (int j = 0; j < 4; ++j)
            sm[SH_H1 + tk * 128 + (c0 + u * 64 + j)] = pm[u][j];
    __syncthreads();
    if (t < 128) {
        float m = sm[SH_H1 + 0 * 128 + t];
#pragma unroll
        for (int w = 1; w < 16; ++w) m = fmaxf(m, sm[SH_H1 + w * 128 + t]);
        out_x[(size_t)c * 128 + t] = m;
    }
}

extern "C" void kernel_launch(void* const* d_in, const int* in_sizes, int n_in,
                              void* d_out, int out_size, void* d_ws, size_t ws_size,
                              hipStream_t stream)
{
    const float* x   = (const float*)d_in[0];
    const float* pos = (const float*)d_in[1];
    // d_in[2] = batch (derived analytically), d_in[9] = num_graphs (constant 8)
    const float* W1 = (const float*)d_in[3];
    const float* b1 = (const float*)d_in[4];
    const float* W2 = (const float*)d_in[5];
    const float* b2 = (const float*)d_in[6];
    const float* W3 = (const float*)d_in[7];
    const float* b3 = (const float*)d_in[8];

    float* out_x     = (float*)d_out;                    // [8192,128]
    float* out_pos   = out_x + (size_t)MTOT * 128;       // [8192,3]
    float* out_batch = out_pos + (size_t)MTOT * 3;       // [8192]

    int* sel = (int*)d_ws;                               // [8192]
    int* nbr = sel + MTOT;                               // [8192*64]
    int* cnt = nbr + (size_t)MTOT * KNN;                 // [8192]

    fps_kernel<<<NB, 1024, 0, stream>>>(pos, sel);
    ballq_kernel<<<MTOT / 4, 256, 0, stream>>>(pos, sel, nbr, cnt, out_pos, out_batch);
    mlp_kernel<<<MTOT, 256, 0, stream>>>(x, pos, nbr, cnt, out_pos,
                                         W1, b1, W2, b2, W3, b3, out_x);
}

// Round 2
// 999.649 us; speedup vs baseline: 2.6941x; 2.6941x over previous
//
#include <hip/hip_runtime.h>
#include <math.h>

#define NB   8
#define NPTS 4096
#define MPER 1024
#define MTOT (NB*MPER)
#define CIN  64
#define KNN  64
#define CAP  512
// (0.2*0.2) computed in double, as the reference's python-float R*R
#define R2D  0.04000000000000001

// exact IEEE fp32 distance, reference order: ((dx*dx + dy*dy) + dz*dz), no FMA
__device__ __forceinline__ float d2f(float ax, float ay, float az,
                                     float bx, float by, float bz) {
    float dx = __fsub_rn(ax, bx);
    float dy = __fsub_rn(ay, by);
    float dz = __fsub_rn(az, bz);
    return __fadd_rn(__fadd_rn(__fmul_rn(dx, dx), __fmul_rn(dy, dy)),
                     __fmul_rn(dz, dz));
}

// full-wave (64-lane) max reduction of a u64 key via DPP; result valid in lane 63.
// canonical gfx9 sequence: row_shr 1,2,4,8 then row_bcast15 (rmask 0xa),
// row_bcast31 (rmask 0xc). identity = 0 (all real keys are > 0).
__device__ __forceinline__ unsigned long long wave_max_u64_dpp(unsigned long long key)
{
#define DPPMAX(ctrl, rmask) do {                                                   \
        unsigned int lo_ = (unsigned int)key;                                      \
        unsigned int hi_ = (unsigned int)(key >> 32);                              \
        unsigned int plo = (unsigned int)__builtin_amdgcn_update_dpp(              \
            0, (int)lo_, ctrl, rmask, 0xf, false);                                 \
        unsigned int phi = (unsigned int)__builtin_amdgcn_update_dpp(              \
            0, (int)hi_, ctrl, rmask, 0xf, false);                                 \
        unsigned long long pk = ((unsigned long long)phi << 32) | plo;             \
        if (pk > key) key = pk;                                                    \
    } while (0)
    DPPMAX(0x111, 0xf);   // row_shr:1
    DPPMAX(0x112, 0xf);   // row_shr:2
    DPPMAX(0x114, 0xf);   // row_shr:4
    DPPMAX(0x118, 0xf);   // row_shr:8
    DPPMAX(0x142, 0xa);   // row_bcast:15 -> rows 1,3
    DPPMAX(0x143, 0xc);   // row_bcast:31 -> rows 2,3
#undef DPPMAX
    return key;
}

// ---------------- Kernel 1: farthest point sampling ----------------
// one block per cloud; 256 threads (4 waves), 16 points/thread in registers.
// per iteration: local argmax in regs -> DPP wave reduce -> 1 barrier ->
// redundant 4-way final reduce -> broadcast LDS coord fetch.
__global__ __launch_bounds__(256) void fps_kernel(const float* __restrict__ pos,
                                                  int* __restrict__ sel)
{
    const int b    = blockIdx.x;
    const int t    = threadIdx.x;
    const int lane = t & 63;
    const int wv   = t >> 6;
    const float* pb = pos + (size_t)b * NPTS * 3;

    __shared__ float lx[NPTS], ly[NPTS], lz[NPTS];
    __shared__ unsigned long long part[2][4];

    float px[16], py[16], pz[16], mind[16];
#pragma unroll
    for (int r = 0; r < 16; ++r) {
        int j = r * 256 + t;
        float x = pb[j * 3 + 0];
        float y = pb[j * 3 + 1];
        float z = pb[j * 3 + 2];
        px[r] = x; py[r] = y; pz[r] = z;
        mind[r] = 3.0e38f;   // first min() yields exactly d2-to-p0
        lx[j] = x; ly[j] = y; lz[j] = z;
    }
    if (t == 0) sel[b * MPER + 0] = b * NPTS + 0;
    __syncthreads();

    float cx = lx[0], cy = ly[0], cz = lz[0];

    for (int it = 1; it < MPER; ++it) {
        // local: update running min-dist, track argmax (ascending j + strict >
        // keeps the lowest index on ties, matching jnp.argmax)
        float bv = -1.0f; int bi = 0;
#pragma unroll
        for (int r = 0; r < 16; ++r) {
            float d2 = d2f(px[r], py[r], pz[r], cx, cy, cz);
            float m = fminf(mind[r], d2);
            mind[r] = m;
            if (m > bv) { bv = m; bi = r * 256 + t; }
        }
        // pack (d2 bits, ~idx): max key == (max d2, then min idx). d2>=0 so
        // float bits are order-isomorphic; key is always > 0.
        unsigned long long key =
            ((unsigned long long)__float_as_uint(bv) << 32) | (unsigned int)(~bi);
        key = wave_max_u64_dpp(key);

        const int p = it & 1;
        if (lane == 63) part[p][wv] = key;
        __syncthreads();

        unsigned long long k0 = part[p][0];
        unsigned long long k1 = part[p][1];
        unsigned long long k2 = part[p][2];
        unsigned long long k3 = part[p][3];
        unsigned long long ka = k0 > k1 ? k0 : k1;
        unsigned long long kb = k2 > k3 ? k2 : k3;
        unsigned long long km = ka > kb ? ka : kb;
        int pick = (int)(~(unsigned int)km);

        cx = lx[pick]; cy = ly[pick]; cz = lz[pick];
        if (t == 0) sel[b * MPER + it] = b * NPTS + pick;
    }
}

// ---------------- Kernel 2: ball query + K nearest (rank select) ----------------
// one wave per centroid, 4 waves / block
__global__ __launch_bounds__(256) void ballq_kernel(
    const float* __restrict__ pos, const int* __restrict__ sel,
    int* __restrict__ nbr, int* __restrict__ cnt,
    float* __restrict__ out_pos, float* __restrict__ out_batch)
{
    __shared__ float cd[4][CAP];
    __shared__ int   ci[4][CAP];

    const int wv   = threadIdx.x >> 6;
    const int lane = threadIdx.x & 63;
    const int c    = blockIdx.x * 4 + wv;
    const int sg   = sel[c];
    const int b    = c >> 10;            // c / MPER
    const int base = b * NPTS;
    const float* pb = pos + (size_t)base * 3;
    const float qx = pos[(size_t)sg * 3 + 0];
    const float qy = pos[(size_t)sg * 3 + 1];
    const float qz = pos[(size_t)sg * 3 + 2];

    int n = 0;
    for (int r0 = 0; r0 < NPTS; r0 += 64) {
        const int j = r0 + lane;
        float x = pb[j * 3 + 0], y = pb[j * 3 + 1], z = pb[j * 3 + 2];
        float d2 = d2f(x, y, z, qx, qy, qz);
        bool inside = ((double)d2 <= R2D);
        unsigned long long m = __ballot(inside);
        if (inside) {
            int myoff = n + __popcll(m & ((1ull << lane) - 1ull));
            if (myoff < CAP) { cd[wv][myoff] = d2; ci[wv][myoff] = j; }
        }
        n += __popcll(m);
    }
    n = min(n, CAP);
    __syncthreads();   // drain LDS writes; all waves structurally aligned here

    // rank = #{j : (dj,ij) <lex (d,id)}  -> matches lax.top_k stable ordering
    for (int i = lane; i < n; i += 64) {
        float d = cd[wv][i]; int id = ci[wv][i];
        int rank = 0;
        for (int j = 0; j < n; ++j) {
            float dj = cd[wv][j]; int ij = ci[wv][j];
            rank += (dj < d || (dj == d && ij < id)) ? 1 : 0;
        }
        if (rank < KNN) nbr[(size_t)c * KNN + rank] = base + id;
    }
    if (lane == 0) {
        cnt[c] = min(n, KNN);
        out_pos[c * 3 + 0] = qx;
        out_pos[c * 3 + 1] = qy;
        out_pos[c * 3 + 2] = qz;
        out_batch[c] = (float)b;
    }
}

// ---------------- Kernel 3: gather + MLP (67->64->64->128) + masked max ----------------
// one block per centroid, 256 threads; fp32 VALU, LDS-staged activations/weights
#define SH_INF 0            // 64*67 = 4288 floats
#define SH_W   4288         // 2048 floats (weight chunk: 32x64 or 16x128)
#define SH_H1  6336         // 64*65 = 4160 floats (stride 65 to spread banks)
#define SH_H2  10496        // 4160 floats
#define SH_TOT 14656        // 58.6 KB

__global__ __launch_bounds__(256) void mlp_kernel(
    const float* __restrict__ x, const float* __restrict__ pos,
    const int* __restrict__ nbr, const int* __restrict__ cnt,
    const float* __restrict__ out_pos,
    const float* __restrict__ W1, const float* __restrict__ b1,
    const float* __restrict__ W2, const float* __restrict__ b2,
    const float* __restrict__ W3, const float* __restrict__ b3,
    float* __restrict__ out_x)
{
    __shared__ float sm[SH_TOT];

    const int c = blockIdx.x;
    const int n = cnt[c];
    const int t = threadIdx.x;

    // ---- stage input features: inf[k][0..66] = [x[nbr_k], pos[nbr_k]-q] ----
    {
        const int k = t >> 2, g = t & 3;
        int nb = (k < n) ? nbr[(size_t)c * KNN + k] : 0;
        float q0 = out_pos[c * 3 + 0], q1 = out_pos[c * 3 + 1], q2 = out_pos[c * 3 + 2];
#pragma unroll
        for (int i = 0; i < 17; ++i) {
            int j = g + 4 * i;
            if (j < 67) {
                float v = 0.0f;
                if (k < n) {
                    if (j < 64) v = x[(size_t)nb * CIN + j];
                    else {
                        float qd = (j == 64) ? q0 : ((j == 65) ? q1 : q2);
                        v = pos[(size_t)nb * 3 + (j - 64)] - qd;   // exact fp32 sub
                    }
                }
                sm[SH_INF + k * 67 + j] = v;
            }
        }
    }

    const int tc = t & 15, tk = t >> 4;
    const int c0 = tc * 4, k0 = tk * 4;

    // ---- layer 1: 67 -> 64, ReLU ----
    float acc[4][4];
    {
        float4 bb = *(const float4*)(b1 + c0);
#pragma unroll
        for (int i = 0; i < 4; ++i) {
            acc[i][0] = bb.x; acc[i][1] = bb.y; acc[i][2] = bb.z; acc[i][3] = bb.w;
        }
        int kk0 = 0;
        for (int ch = 0; ch < 3; ++ch) {
            int rows = min(32, 67 - kk0);
            __syncthreads();
            for (int e = t; e < rows * 64; e += 256) sm[SH_W + e] = W1[kk0 * 64 + e];
            __syncthreads();
            for (int r = 0; r < rows; ++r) {
                int kk = kk0 + r;
                float4 w = *(const float4*)&sm[SH_W + r * 64 + c0];
                float in0 = sm[SH_INF + (k0 + 0) * 67 + kk];
                float in1 = sm[SH_INF + (k0 + 1) * 67 + kk];
                float in2 = sm[SH_INF + (k0 + 2) * 67 + kk];
                float in3 = sm[SH_INF + (k0 + 3) * 67 + kk];
                acc[0][0] = fmaf(in0, w.x, acc[0][0]); acc[0][1] = fmaf(in0, w.y, acc[0][1]);
                acc[0][2] = fmaf(in0, w.z, acc[0][2]); acc[0][3] = fmaf(in0, w.w, acc[0][3]);
                acc[1][0] = fmaf(in1, w.x, acc[1][0]); acc[1][1] = fmaf(in1, w.y, acc[1][1]);
                acc[1][2] = fmaf(in1, w.z, acc[1][2]); acc[1][3] = fmaf(in1, w.w, acc[1][3]);
                acc[2][0] = fmaf(in2, w.x, acc[2][0]); acc[2][1] = fmaf(in2, w.y, acc[2][1]);
                acc[2][2] = fmaf(in2, w.z, acc[2][2]); acc[2][3] = fmaf(in2, w.w, acc[2][3]);
                acc[3][0] = fmaf(in3, w.x, acc[3][0]); acc[3][1] = fmaf(in3, w.y, acc[3][1]);
                acc[3][2] = fmaf(in3, w.z, acc[3][2]); acc[3][3] = fmaf(in3, w.w, acc[3][3]);
            }
            kk0 += rows;
        }
#pragma unroll
        for (int i = 0; i < 4; ++i)
#pragma unroll
            for (int j = 0; j < 4; ++j)
                sm[SH_H1 + (k0 + i) * 65 + (c0 + j)] = fmaxf(acc[i][j], 0.0f);
    }

    // ---- layer 2: 64 -> 64, ReLU ----
    {
        float4 bb = *(const float4*)(b2 + c0);
#pragma unroll
        for (int i = 0; i < 4; ++i) {
            acc[i][0] = bb.x; acc[i][1] = bb.y; acc[i][2] = bb.z; acc[i][3] = bb.w;
        }
        for (int ch = 0; ch < 2; ++ch) {
            __syncthreads();
            for (int e = t; e < 32 * 64; e += 256) sm[SH_W + e] = W2[ch * 2048 + e];
            __syncthreads();
            for (int r = 0; r < 32; ++r) {
                int kk = ch * 32 + r;
                float4 w = *(const float4*)&sm[SH_W + r * 64 + c0];
                float in0 = sm[SH_H1 + (k0 + 0) * 65 + kk];
                float in1 = sm[SH_H1 + (k0 + 1) * 65 + kk];
                float in2 = sm[SH_H1 + (k0 + 2) * 65 + kk];
                float in3 = sm[SH_H1 + (k0 + 3) * 65 + kk];
                acc[0][0] = fmaf(in0, w.x, acc[0][0]); acc[0][1] = fmaf(in0, w.y, acc[0][1]);
                acc[0][2] = fmaf(in0, w.z, acc[0][2]); acc[0][3] = fmaf(in0, w.w, acc[0][3]);
                acc[1][0] = fmaf(in1, w.x, acc[1][0]); acc[1][1] = fmaf(in1, w.y, acc[1][1]);
                acc[1][2] = fmaf(in1, w.z, acc[1][2]); acc[1][3] = fmaf(in1, w.w, acc[1][3]);
                acc[2][0] = fmaf(in2, w.x, acc[2][0]); acc[2][1] = fmaf(in2, w.y, acc[2][1]);
                acc[2][2] = fmaf(in2, w.z, acc[2][2]); acc[2][3] = fmaf(in2, w.w, acc[2][3]);
                acc[3][0] = fmaf(in3, w.x, acc[3][0]); acc[3][1] = fmaf(in3, w.y, acc[3][1]);
                acc[3][2] = fmaf(in3, w.z, acc[3][2]); acc[3][3] = fmaf(in3, w.w, acc[3][3]);
            }
        }
        __syncthreads();
#pragma unroll
        for (int i = 0; i < 4; ++i)
#pragma unroll
            for (int j = 0; j < 4; ++j)
                sm[SH_H2 + (k0 + i) * 65 + (c0 + j)] = fmaxf(acc[i][j], 0.0f);
    }

    // ---- layer 3: 64 -> 128 (two c-tiles per thread) ----
    float acc3[2][4][4];
    {
#pragma unroll
        for (int u = 0; u < 2; ++u) {
            float4 bb = *(const float4*)(b3 + c0 + u * 64);
#pragma unroll
            for (int i = 0; i < 4; ++i) {
                acc3[u][i][0] = bb.x; acc3[u][i][1] = bb.y;
                acc3[u][i][2] = bb.z; acc3[u][i][3] = bb.w;
            }
        }
        for (int ch = 0; ch < 4; ++ch) {
            __syncthreads();
            for (int e = t; e < 16 * 128; e += 256) sm[SH_W + e] = W3[ch * 2048 + e];
            __syncthreads();
            for (int r = 0; r < 16; ++r) {
                int kk = ch * 16 + r;
                float4 wa = *(const float4*)&sm[SH_W + r * 128 + c0];
                float4 wb = *(const float4*)&sm[SH_W + r * 128 + c0 + 64];
                float in0 = sm[SH_H2 + (k0 + 0) * 65 + kk];
                float in1 = sm[SH_H2 + (k0 + 1) * 65 + kk];
                float in2 = sm[SH_H2 + (k0 + 2) * 65 + kk];
                float in3 = sm[SH_H2 + (k0 + 3) * 65 + kk];
                acc3[0][0][0] = fmaf(in0, wa.x, acc3[0][0][0]); acc3[0][0][1] = fmaf(in0, wa.y, acc3[0][0][1]);
                acc3[0][0][2] = fmaf(in0, wa.z, acc3[0][0][2]); acc3[0][0][3] = fmaf(in0, wa.w, acc3[0][0][3]);
                acc3[0][1][0] = fmaf(in1, wa.x, acc3[0][1][0]); acc3[0][1][1] = fmaf(in1, wa.y, acc3[0][1][1]);
                acc3[0][1][2] = fmaf(in1, wa.z, acc3[0][1][2]); acc3[0][1][3] = fmaf(in1, wa.w, acc3[0][1][3]);
                acc3[0][2][0] = fmaf(in2, wa.x, acc3[0][2][0]); acc3[0][2][1] = fmaf(in2, wa.y, acc3[0][2][1]);
                acc3[0][2][2] = fmaf(in2, wa.z, acc3[0][2][2]); acc3[0][2][3] = fmaf(in2, wa.w, acc3[0][2][3]);
                acc3[0][3][0] = fmaf(in3, wa.x, acc3[0][3][0]); acc3[0][3][1] = fmaf(in3, wa.y, acc3[0][3][1]);
                acc3[0][3][2] = fmaf(in3, wa.z, acc3[0][3][2]); acc3[0][3][3] = fmaf(in3, wa.w, acc3[0][3][3]);
                acc3[1][0][0] = fmaf(in0, wb.x, acc3[1][0][0]); acc3[1][0][1] = fmaf(in0, wb.y, acc3[1][0][1]);
                acc3[1][0][2] = fmaf(in0, wb.z, acc3[1][0][2]); acc3[1][0][3] = fmaf(in0, wb.w, acc3[1][0][3]);
                acc3[1][1][0] = fmaf(in1, wb.x, acc3[1][1][0]); acc3[1][1][1] = fmaf(in1, wb.y, acc3[1][1][1]);
                acc3[1][1][2] = fmaf(in1, wb.z, acc3[1][1][2]); acc3[1][1][3] = fmaf(in1, wb.w, acc3[1][1][3]);
                acc3[1][2][0] = fmaf(in2, wb.x, acc3[1][2][0]); acc3[1][2][1] = fmaf(in2, wb.y, acc3[1][2][1]);
                acc3[1][2][2] = fmaf(in2, wb.z, acc3[1][2][2]); acc3[1][2][3] = fmaf(in2, wb.w, acc3[1][2][3]);
                acc3[1][3][0] = fmaf(in3, wb.x, acc3[1][3][0]); acc3[1][3][1] = fmaf(in3, wb.y, acc3[1][3][1]);
                acc3[1][3][2] = fmaf(in3, wb.z, acc3[1][3][2]); acc3[1][3][3] = fmaf(in3, wb.w, acc3[1][3][3]);
            }
        }
    }

    // ---- masked max over k (k < n), tree-reduced via LDS partials ----
    float pm[2][4];
#pragma unroll
    for (int u = 0; u < 2; ++u)
#pragma unroll
        for (int j = 0; j < 4; ++j) pm[u][j] = -1e30f;
#pragma unroll
    for (int i = 0; i < 4; ++i) {
        if (k0 + i < n) {
#pragma unroll
            for (int u = 0; u < 2; ++u)
#pragma unroll
                for (int j = 0; j < 4; ++j) pm[u][j] = fmaxf(pm[u][j], acc3[u][i][j]);
        }
    }
    __syncthreads();   // h1 region is dead; reuse as [16][128] partials
#pragma unroll
    for (int u = 0; u < 2; ++u)
#pragma unroll
        for (int j = 0; j < 4; ++j)
            sm[SH_H1 + tk * 128 + (c0 + u * 64 + j)] = pm[u][j];
    __syncthreads();
    if (t < 128) {
        float m = sm[SH_H1 + 0 * 128 + t];
#pragma unroll
        for (int w = 1; w < 16; ++w) m = fmaxf(m, sm[SH_H1 + w * 128 + t]);
        out_x[(size_t)c * 128 + t] = m;
    }
}

extern "C" void kernel_launch(void* const* d_in, const int* in_sizes, int n_in,
                              void* d_out, int out_size, void* d_ws, size_t ws_size,
                              hipStream_t stream)
{
    const float* x   = (const float*)d_in[0];
    const float* pos = (const float*)d_in[1];
    // d_in[2] = batch (derived analytically), d_in[9] = num_graphs (constant 8)
    const float* W1 = (const float*)d_in[3];
    const float* b1 = (const float*)d_in[4];
    const float* W2 = (const float*)d_in[5];
    const float* b2 = (const float*)d_in[6];
    const float* W3 = (const float*)d_in[7];
    const float* b3 = (const float*)d_in[8];

    float* out_x     = (float*)d_out;                    // [8192,128]
    float* out_pos   = out_x + (size_t)MTOT * 128;       // [8192,3]
    float* out_batch = out_pos + (size_t)MTOT * 3;       // [8192]

    int* sel = (int*)d_ws;                               // [8192]
    int* nbr = sel + MTOT;                               // [8192*64]
    int* cnt = nbr + (size_t)MTOT * KNN;                 // [8192]

    fps_kernel<<<NB, 256, 0, stream>>>(pos, sel);
    ballq_kernel<<<MTOT / 4, 256, 0, stream>>>(pos, sel, nbr, cnt, out_pos, out_batch);
    mlp_kernel<<<MTOT, 256, 0, stream>>>(x, pos, nbr, cnt, out_pos,
                                         W1, b1, W2, b2, W3, b3, out_x);
}